// Round 2
// baseline (414.070 us; speedup 1.0000x reference)
//
#include <hip/hip_runtime.h>
#include <hip/hip_bf16.h>

typedef unsigned short u16;
typedef short s8v __attribute__((ext_vector_type(8)));
typedef float f4v __attribute__((ext_vector_type(4)));

#define F 128
#define CIN 1024
#define CMID 512
#define XP 130
#define K9 9216
#define LDA 40   // 32 bf16 data + 8 pad; row = 80B, 16B-aligned rows

__device__ __forceinline__ u16 f2bf(float v) {
    union { float f; unsigned u; } x; x.f = v;
    unsigned r = x.u + 0x7fff + ((x.u >> 16) & 1);
    return (u16)(r >> 16);
}
__device__ __forceinline__ float bf2f(u16 u) {
    union { unsigned u; float f; } x; x.u = ((unsigned)u) << 16; return x.f;
}

// anchor base sizes: ratios {0.5,1,2} x scales {8,16,32}
__constant__ float WBASE[9] = {184.f, 368.f, 736.f, 128.f, 256.f, 512.f,  88.f, 176.f, 352.f};
__constant__ float HBASE[9] = { 96.f, 192.f, 384.f, 128.f, 256.f, 512.f, 176.f, 352.f, 704.f};

// ---------------- prep: zero xpad border cells -----------------------------
__global__ void prep_border(u16* __restrict__ xpad) {
    int t = blockIdx.x * 256 + threadIdx.x;      // 516*1024 total
    if (t >= 516 * 1024) return;
    int c = t & 1023;
    int cell = t >> 10;
    int h, w;
    if (cell < 130)      { h = 0;   w = cell; }
    else if (cell < 260) { h = 129; w = cell - 130; }
    else { int rm = cell - 260; h = 1 + (rm >> 1); w = (rm & 1) * 129; }
    xpad[(h * XP + w) * CIN + c] = 0;
}

// ---------------- prep: NCHW fp32 -> padded NHWC bf16 ----------------------
__global__ void prep_xpad(const float* __restrict__ x, u16* __restrict__ xpad) {
    __shared__ float lds[64][65];
    const int h  = blockIdx.x;        // 0..127
    const int w0 = blockIdx.y * 64;   // 0,64
    const int c0 = blockIdx.z * 64;   // 0..960
    const int tid = threadIdx.x;
    {
        const int wl = tid & 63, ci = tid >> 6;       // ci 0..3
        #pragma unroll
        for (int k = 0; k < 16; ++k) {
            int cl = ci * 16 + k;
            lds[cl][wl] = x[(c0 + cl) * (F * F) + h * F + (w0 + wl)];
        }
    }
    __syncthreads();
    {
        const int cl = tid & 63, wi = tid >> 6;
        #pragma unroll
        for (int k = 0; k < 16; ++k) {
            int wl = wi * 16 + k;
            xpad[((h + 1) * XP + (w0 + wl + 1)) * CIN + (c0 + cl)] = f2bf(lds[cl][wl]);
        }
    }
}

// ---------------- prep: base_w OIHW fp32 -> [oc][dydx][c] bf16 -------------
__global__ void prep_wt(const float* __restrict__ bw, u16* __restrict__ wt) {
    __shared__ u16 lds[K9];
    const int oc = blockIdx.x;
    const int tid = threadIdx.x;
    for (int k = 0; k < 36; ++k) {
        int idx = k * 256 + tid;                  // (c,dy,dx) linear, c-major
        float v = bw[oc * K9 + idx];
        int c = idx / 9, q = idx - c * 9;
        lds[q * CIN + c] = f2bf(v);
    }
    __syncthreads();
    for (int k = 0; k < 36; ++k) {
        int idx = k * 256 + tid;
        wt[oc * K9 + idx] = lds[idx];
    }
}

// ---------------- prep: combined 1x1 weights (18 cls + 36 reg, pad to 64) --
__global__ void prep_wc(const float* __restrict__ cls_w, const float* __restrict__ reg_w,
                        u16* __restrict__ wc) {
    int t = blockIdx.x * 256 + threadIdx.x;       // 64*512
    int oc = t >> 9, c = t & 511;
    float v = 0.f;
    if (oc < 18)      v = cls_w[oc * 512 + c];
    else if (oc < 54) v = reg_w[(oc - 18) * 512 + c];
    wc[t] = f2bf(v);
}

// ---------------- stage 1: implicit-GEMM 3x3 conv + bias + ReLU ------------
// M = 16384 positions (tile 128 = one image row h), N = 512 oc (tile 128),
// K = 9216 = 9 (dy,dx) x 1024 c, BK = 32.
// Staging: 256 threads, 2 threads/row, each stages 16 elems (two s8v) per matrix.
__global__ __launch_bounds__(256, 2) void gemm_conv(
    const u16* __restrict__ xpad, const u16* __restrict__ wt,
    const float* __restrict__ bias, u16* __restrict__ rpn) {
    __shared__ u16 Asm[128 * LDA];
    __shared__ u16 Bsm[128 * LDA];
    const int tid = threadIdx.x;
    const int gh  = blockIdx.x;          // row h
    const int oc0 = blockIdx.y * 128;

    const int r   = tid >> 1;            // staging row 0..127
    const int seg = (tid & 1) * 16;      // 0/16 (elements within the 32-elem row)

    const int lane = tid & 63;
    const int wv = tid >> 6;
    const int lm = lane & 15;
    const int lq = lane >> 4;
    const int wm = (wv >> 1) * 64;       // wave m-offset in tile
    const int wn = (wv & 1) * 64;        // wave n-offset in tile

    f4v acc[4][4] = {};

    for (int dydx = 0; dydx < 9; ++dydx) {
        const int dy = dydx / 3, dx = dydx - dy * 3;
        const u16* ga_base = xpad + ((gh + dy) * XP + (r + dx)) * CIN + seg;
        const u16* gb_base = wt + (oc0 + r) * K9 + dydx * CIN + seg;
        for (int cc = 0; cc < 32; ++cc) {
            const int c0 = cc * 32;
            *(s8v*)&Asm[r * LDA + seg]     = *(const s8v*)(ga_base + c0);
            *(s8v*)&Asm[r * LDA + seg + 8] = *(const s8v*)(ga_base + c0 + 8);
            *(s8v*)&Bsm[r * LDA + seg]     = *(const s8v*)(gb_base + c0);
            *(s8v*)&Bsm[r * LDA + seg + 8] = *(const s8v*)(gb_base + c0 + 8);
            __syncthreads();
            s8v af[4], bfr[4];
            #pragma unroll
            for (int i = 0; i < 4; ++i) {
                af[i]  = *(const s8v*)&Asm[(wm + i * 16 + lm) * LDA + lq * 8];
                bfr[i] = *(const s8v*)&Bsm[(wn + i * 16 + lm) * LDA + lq * 8];
            }
            #pragma unroll
            for (int mi = 0; mi < 4; ++mi)
                #pragma unroll
                for (int ni = 0; ni < 4; ++ni)
                    acc[mi][ni] = __builtin_amdgcn_mfma_f32_16x16x32_bf16(
                        af[mi], bfr[ni], acc[mi][ni], 0, 0, 0);
            __syncthreads();
        }
    }
    // epilogue: D[m][n]: m = lq*4+rr (+16mi+wm), n = lm (+16ni+wn)
    #pragma unroll
    for (int ni = 0; ni < 4; ++ni) {
        const int oc = oc0 + wn + ni * 16 + lm;
        const float b = bias[oc];
        #pragma unroll
        for (int mi = 0; mi < 4; ++mi) {
            #pragma unroll
            for (int rr = 0; rr < 4; ++rr) {
                const int m = wm + mi * 16 + lq * 4 + rr;   // w index
                float v = acc[mi][ni][rr] + b;
                v = v > 0.f ? v : 0.f;
                rpn[(gh * 128 + m) * CMID + oc] = f2bf(v);
            }
        }
    }
}

// ---------------- stage 2: 1x1 convs + softmax + proposals -----------------
// one wave per position p; lane owns 8 channels of rpn[p][:]
__global__ __launch_bounds__(256) void stage2(
    const u16* __restrict__ rpn, const u16* __restrict__ wc,
    const float* __restrict__ cls_b, const float* __restrict__ reg_b,
    float* __restrict__ out) {
    __shared__ float vals[4][56];
    const int tid = threadIdx.x;
    const int wv = tid >> 6, lane = tid & 63;
    const int p = blockIdx.x * 4 + wv;

    s8v rv = *(const s8v*)&rpn[p * CMID + lane * 8];
    float rf[8];
    #pragma unroll
    for (int j = 0; j < 8; ++j) rf[j] = bf2f((u16)rv[j]);

    for (int oc = 0; oc < 54; ++oc) {
        s8v wvv = *(const s8v*)&wc[oc * CMID + lane * 8];
        float s = 0.f;
        #pragma unroll
        for (int j = 0; j < 8; ++j) s += rf[j] * bf2f((u16)wvv[j]);
        #pragma unroll
        for (int off = 32; off; off >>= 1) s += __shfl_xor(s, off, 64);
        if (lane == 0) {
            float b = (oc < 18) ? cls_b[oc] : reg_b[oc - 18];
            vals[wv][oc] = s + b;
        }
    }
    __syncthreads();
    if (lane < 9) {
        const int a = lane;
        const float* v = vals[wv];
        const int ch = 2 * a + 1;
        const int pair = (ch < 9) ? ch + 9 : ch - 9;
        const float score = 1.f / (1.f + expf(v[pair] - v[ch]));
        const float r0 = v[18 + 4 * a], r1 = v[19 + 4 * a];
        const float r2 = v[20 + 4 * a], r3 = v[21 + 4 * a];
        const float wb = WBASE[a], hb = HBASE[a];
        const int h = p >> 7, w = p & 127;
        float* o = out + (p * 9 + a) * 5;
        o[0] = h * 16.f + wb * r0;
        o[1] = w * 16.f + hb * r1;
        o[2] = wb + expf(r2);
        o[3] = hb + expf(r3);
        o[4] = score;
    }
}

extern "C" void kernel_launch(void* const* d_in, const int* in_sizes, int n_in,
                              void* d_out, int out_size, void* d_ws, size_t ws_size,
                              hipStream_t stream) {
    const float* x      = (const float*)d_in[0];
    const float* base_w = (const float*)d_in[1];
    const float* base_b = (const float*)d_in[2];
    const float* cls_w  = (const float*)d_in[3];
    const float* cls_b  = (const float*)d_in[4];
    const float* reg_w  = (const float*)d_in[5];
    const float* reg_b  = (const float*)d_in[6];
    float* out = (float*)d_out;

    char* ws = (char*)d_ws;
    u16* xpad = (u16*)ws;                                   // 130*130*1024*2 = 34,611,200 B
    u16* wt   = (u16*)(ws + 34611200);                      // 512*9216*2     =  9,437,184 B
    u16* wc   = (u16*)(ws + 34611200 + 9437184);            // 64*512*2       =     65,536 B
    u16* rpn  = (u16*)(ws + 34611200 + 9437184 + 65536);    // 16384*512*2    = 16,777,216 B

    prep_border<<<2064, 256, 0, stream>>>(xpad);
    prep_xpad<<<dim3(128, 2, 16), 256, 0, stream>>>(x, xpad);
    prep_wt<<<512, 256, 0, stream>>>(base_w, wt);
    prep_wc<<<128, 256, 0, stream>>>(cls_w, reg_w, wc);
    gemm_conv<<<dim3(128, 4), 256, 0, stream>>>(xpad, wt, base_b, rpn);
    stage2<<<4096, 256, 0, stream>>>(rpn, wc, cls_b, reg_b, out);
}

// Round 3
// 278.652 us; speedup vs baseline: 1.4860x; 1.4860x over previous
//
#include <hip/hip_runtime.h>
#include <hip/hip_bf16.h>

typedef unsigned short u16;
typedef short s8v __attribute__((ext_vector_type(8)));
typedef float f4v __attribute__((ext_vector_type(4)));

#define F 128
#define CIN 1024
#define CMID 512
#define XP 130
#define K9 9216
#define BK 64

__device__ __forceinline__ u16 f2bf(float v) {
    union { float f; unsigned u; } x; x.f = v;
    unsigned r = x.u + 0x7fff + ((x.u >> 16) & 1);
    return (u16)(r >> 16);
}
__device__ __forceinline__ float bf2f(u16 u) {
    union { unsigned u; float f; } x; x.u = ((unsigned)u) << 16; return x.f;
}

__device__ __forceinline__ void gl16(const u16* g, u16* l) {
    __builtin_amdgcn_global_load_lds(
        (const __attribute__((address_space(1))) void*)g,
        (__attribute__((address_space(3))) void*)l,
        16, 0, 0);
}

// anchor base sizes: ratios {0.5,1,2} x scales {8,16,32}
__constant__ float WBASE[9] = {184.f, 368.f, 736.f, 128.f, 256.f, 512.f,  88.f, 176.f, 352.f};
__constant__ float HBASE[9] = { 96.f, 192.f, 384.f, 128.f, 256.f, 512.f, 176.f, 352.f, 704.f};

// ---------------- prep: zero xpad border cells -----------------------------
__global__ void prep_border(u16* __restrict__ xpad) {
    int t = blockIdx.x * 256 + threadIdx.x;      // 516*1024 total
    if (t >= 516 * 1024) return;
    int c = t & 1023;
    int cell = t >> 10;
    int h, w;
    if (cell < 130)      { h = 0;   w = cell; }
    else if (cell < 260) { h = 129; w = cell - 130; }
    else { int rm = cell - 260; h = 1 + (rm >> 1); w = (rm & 1) * 129; }
    xpad[(h * XP + w) * CIN + c] = 0;
}

// ---------------- prep: NCHW fp32 -> padded NHWC bf16 ----------------------
__global__ void prep_xpad(const float* __restrict__ x, u16* __restrict__ xpad) {
    __shared__ float lds[64][65];
    const int h  = blockIdx.x;        // 0..127
    const int w0 = blockIdx.y * 64;   // 0,64
    const int c0 = blockIdx.z * 64;   // 0..960
    const int tid = threadIdx.x;
    {
        const int wl = tid & 63, ci = tid >> 6;       // ci 0..3
        #pragma unroll
        for (int k = 0; k < 16; ++k) {
            int cl = ci * 16 + k;
            lds[cl][wl] = x[(c0 + cl) * (F * F) + h * F + (w0 + wl)];
        }
    }
    __syncthreads();
    {
        const int cs = (tid & 7) * 8;                 // c-seg of 8
        #pragma unroll
        for (int pass = 0; pass < 2; ++pass) {
            const int wl = (tid >> 3) + pass * 32;    // 0..63
            s8v v;
            #pragma unroll
            for (int j = 0; j < 8; ++j) v[j] = (short)f2bf(lds[cs + j][wl]);
            *(s8v*)&xpad[((h + 1) * XP + (w0 + wl + 1)) * CIN + c0 + cs] = v;
        }
    }
}

// ---------------- prep: base_w OIHW fp32 -> [oc][dydx][c] bf16 -------------
__global__ void prep_wt(const float* __restrict__ bw, u16* __restrict__ wt) {
    __shared__ u16 lds[K9];
    const int oc = blockIdx.x;
    const int tid = threadIdx.x;
    for (int k = 0; k < 36; ++k) {
        int idx = k * 256 + tid;                  // (c,dy,dx) linear, c-major
        float v = bw[oc * K9 + idx];
        int c = idx / 9, q = idx - c * 9;
        lds[q * CIN + c] = f2bf(v);
    }
    __syncthreads();
    for (int k = 0; k < 36; ++k) {
        int idx = k * 256 + tid;
        wt[oc * K9 + idx] = lds[idx];
    }
}

// ---------------- prep: combined 1x1 weights (18 cls + 36 reg, pad to 64) --
__global__ void prep_wc(const float* __restrict__ cls_w, const float* __restrict__ reg_w,
                        u16* __restrict__ wc) {
    int t = blockIdx.x * 256 + threadIdx.x;       // 64*512
    int oc = t >> 9, c = t & 511;
    float v = 0.f;
    if (oc < 18)      v = cls_w[oc * 512 + c];
    else if (oc < 54) v = reg_w[(oc - 18) * 512 + c];
    wc[t] = f2bf(v);
}

// ---------------- stage 1: implicit-GEMM 3x3 conv + bias + ReLU ------------
// M = 16384 (tile 128 = one image row), N = 512 (tile 128), K = 9216,
// BK = 64. global_load_lds(16B) staging, XOR-swizzled LDS, double-buffered.
// LDS row r (64 elems = 8 segs of 16B): data seg s stored at position s^(r&7).
__global__ __launch_bounds__(256, 2) void gemm_conv(
    const u16* __restrict__ xpad, const u16* __restrict__ wt,
    const float* __restrict__ bias, u16* __restrict__ rpn) {
    __shared__ u16 smem[4 * 128 * BK];   // [buf][A/B][128*BK] = 64 KB
    const int tid = threadIdx.x;
    const int gh  = blockIdx.x;          // image row h
    const int oc0 = blockIdx.y * 128;

    const int lane = tid & 63;
    const int wv = tid >> 6;
    const int lm = lane & 15;
    const int lq = lane >> 4;
    const int wm = (wv >> 1) * 64;
    const int wn = (wv & 1) * 64;

    // staging geometry: wave w covers rows [w*32, w*32+32), 4 chunks of 8 rows
    const u16* pa[4];                    // per-thread source base (A)
    const u16* pb[4];                    // per-thread source base (B)
    #pragma unroll
    for (int j = 0; j < 4; ++j) {
        int r = wv * 32 + j * 8 + (lane >> 3);
        int s8 = ((lane & 7) ^ (r & 7)) * 8;
        pa[j] = xpad + r * CIN + s8;                    // + ((gh+dy)*XP+dx)*CIN + c0
        pb[j] = wt + (size_t)(oc0 + r) * K9 + s8;       // + dydx*CIN + c0
    }

    f4v acc[4][4] = {};

    auto issue = [&](int step, int buf) {
        const int dydx = step >> 4;
        const int cc   = step & 15;
        const int dy = dydx / 3, dx = dydx - dy * 3;
        const int aoff = ((gh + dy) * XP + dx) * CIN + cc * 64;
        const int boff = dydx * CIN + cc * 64;
        u16* Ab = smem + (buf * 2 + 0) * (128 * BK) + (wv * 32) * BK;
        u16* Bb = smem + (buf * 2 + 1) * (128 * BK) + (wv * 32) * BK;
        #pragma unroll
        for (int j = 0; j < 4; ++j) {
            gl16(pa[j] + aoff, Ab + j * 8 * BK);
            gl16(pb[j] + boff, Bb + j * 8 * BK);
        }
    };

    issue(0, 0);
    __syncthreads();
    for (int step = 0; step < 144; ++step) {
        const int buf = step & 1;
        if (step + 1 < 144) issue(step + 1, buf ^ 1);
        const u16* Ab = smem + (buf * 2 + 0) * (128 * BK);
        const u16* Bb = smem + (buf * 2 + 1) * (128 * BK);
        #pragma unroll
        for (int kk = 0; kk < 2; ++kk) {
            s8v af[4], bfr[4];
            #pragma unroll
            for (int i = 0; i < 4; ++i) {
                int ra = wm + i * 16 + lm;
                int rb = wn + i * 16 + lm;
                af[i]  = *(const s8v*)&Ab[ra * BK + (((kk * 4 + lq) ^ (ra & 7)) * 8)];
                bfr[i] = *(const s8v*)&Bb[rb * BK + (((kk * 4 + lq) ^ (rb & 7)) * 8)];
            }
            #pragma unroll
            for (int mi = 0; mi < 4; ++mi)
                #pragma unroll
                for (int ni = 0; ni < 4; ++ni)
                    acc[mi][ni] = __builtin_amdgcn_mfma_f32_16x16x32_bf16(
                        af[mi], bfr[ni], acc[mi][ni], 0, 0, 0);
        }
        __syncthreads();   // drains vmcnt (next-step DMA) + protects LDS reuse
    }

    // epilogue: D[m][n]: m = lq*4+rr (+16mi+wm), n = lm (+16ni+wn)
    #pragma unroll
    for (int ni = 0; ni < 4; ++ni) {
        const int oc = oc0 + wn + ni * 16 + lm;
        const float b = bias[oc];
        #pragma unroll
        for (int mi = 0; mi < 4; ++mi) {
            #pragma unroll
            for (int rr = 0; rr < 4; ++rr) {
                const int m = wm + mi * 16 + lq * 4 + rr;   // w index
                float v = acc[mi][ni][rr] + b;
                v = v > 0.f ? v : 0.f;
                rpn[(gh * 128 + m) * CMID + oc] = f2bf(v);
            }
        }
    }
}

// ---------------- stage 2: 1x1 convs as MFMA GEMM --------------------------
// M=16384 (64/block, 16/wave), N=64 (18 cls + 36 reg + 10 pad), K=512.
// Fragments loaded directly from global (wc is L2-resident).
__global__ __launch_bounds__(256) void stage2(
    const u16* __restrict__ rpn, const u16* __restrict__ wc,
    const float* __restrict__ cls_b, const float* __restrict__ reg_b,
    float* __restrict__ vals) {
    const int tid = threadIdx.x, lane = tid & 63, wv = tid >> 6;
    const int lm = lane & 15, lq = lane >> 4;
    const int m0 = blockIdx.x * 64 + wv * 16;
    f4v acc[4] = {};
    const u16* arow = rpn + (m0 + lm) * CMID + lq * 8;
    const u16* brow = wc + lm * CMID + lq * 8;
    #pragma unroll
    for (int k = 0; k < 16; ++k) {
        s8v af = *(const s8v*)(arow + k * 32);
        #pragma unroll
        for (int ni = 0; ni < 4; ++ni) {
            s8v bf = *(const s8v*)(brow + ni * 16 * CMID + k * 32);
            acc[ni] = __builtin_amdgcn_mfma_f32_16x16x32_bf16(af, bf, acc[ni], 0, 0, 0);
        }
    }
    #pragma unroll
    for (int ni = 0; ni < 4; ++ni) {
        const int ch = ni * 16 + lm;
        const float b = ch < 18 ? cls_b[ch] : (ch < 54 ? reg_b[ch - 18] : 0.f);
        #pragma unroll
        for (int rr = 0; rr < 4; ++rr)
            vals[(m0 + lq * 4 + rr) * 64 + ch] = acc[ni][rr] + b;
    }
}

// ---------------- stage 3: softmax + proposal assembly ---------------------
__global__ void stage3(const float* __restrict__ vals, float* __restrict__ out) {
    const int t = blockIdx.x * 256 + threadIdx.x;   // 147456 = 16384*9
    const int p = t / 9, a = t - p * 9;
    const float* v = vals + p * 64;
    const int ch = 2 * a + 1;
    const int pair = (ch < 9) ? ch + 9 : ch - 9;
    const float score = 1.f / (1.f + expf(v[pair] - v[ch]));
    const float r0 = v[18 + 4 * a], r1 = v[19 + 4 * a];
    const float r2 = v[20 + 4 * a], r3 = v[21 + 4 * a];
    const float wb = WBASE[a], hb = HBASE[a];
    const int h = p >> 7, w = p & 127;
    float* o = out + t * 5;
    o[0] = h * 16.f + wb * r0;
    o[1] = w * 16.f + hb * r1;
    o[2] = wb + expf(r2);
    o[3] = hb + expf(r3);
    o[4] = score;
}

extern "C" void kernel_launch(void* const* d_in, const int* in_sizes, int n_in,
                              void* d_out, int out_size, void* d_ws, size_t ws_size,
                              hipStream_t stream) {
    const float* x      = (const float*)d_in[0];
    const float* base_w = (const float*)d_in[1];
    const float* base_b = (const float*)d_in[2];
    const float* cls_w  = (const float*)d_in[3];
    const float* cls_b  = (const float*)d_in[4];
    const float* reg_w  = (const float*)d_in[5];
    const float* reg_b  = (const float*)d_in[6];
    float* out = (float*)d_out;

    char* ws = (char*)d_ws;
    u16*  xpad = (u16*)ws;                                    // 130*130*1024*2 = 34,611,200 B
    u16*  wt   = (u16*)(ws + 34611200);                       // 512*9216*2     =  9,437,184 B
    u16*  wc   = (u16*)(ws + 34611200 + 9437184);             // 64*512*2       =     65,536 B
    u16*  rpn  = (u16*)(ws + 34611200 + 9437184 + 65536);     // 16384*512*2    = 16,777,216 B
    float* vals = (float*)(ws + 34611200 + 9437184 + 65536 + 16777216); // 16384*64*4 = 4 MB

    prep_border<<<2064, 256, 0, stream>>>(xpad);
    prep_xpad<<<dim3(128, 2, 16), 256, 0, stream>>>(x, xpad);
    prep_wt<<<512, 256, 0, stream>>>(base_w, wt);
    prep_wc<<<128, 256, 0, stream>>>(cls_w, reg_w, wc);
    gemm_conv<<<dim3(128, 4), 256, 0, stream>>>(xpad, wt, base_b, rpn);
    stage2<<<256, 256, 0, stream>>>(rpn, wc, cls_b, reg_b, vals);
    stage3<<<576, 256, 0, stream>>>(vals, out);
}

// Round 5
// 276.388 us; speedup vs baseline: 1.4981x; 1.0082x over previous
//
#include <hip/hip_runtime.h>
#include <hip/hip_bf16.h>

typedef unsigned short u16;
typedef short s8v __attribute__((ext_vector_type(8)));
typedef float f4v __attribute__((ext_vector_type(4)));

#define F 128
#define CIN 1024
#define CMID 512
#define XP 130
#define K9 9216

// gemm LDS element offsets (u16 units)
#define A_ELEMS 8704           // 136 rows * 64
#define B_ELEMS 8192           // 128 rows * 64
#define AOFF(b) ((b) * A_ELEMS)
#define BOFF(b) (2 * A_ELEMS + (b) * B_ELEMS)

__device__ __forceinline__ u16 f2bf(float v) {
    union { float f; unsigned u; } x; x.f = v;
    unsigned r = x.u + 0x7fff + ((x.u >> 16) & 1);
    return (u16)(r >> 16);
}
__device__ __forceinline__ float bf2f(u16 u) {
    union { unsigned u; float f; } x; x.u = ((unsigned)u) << 16; return x.f;
}

__device__ __forceinline__ void gl16(const u16* g, u16* l) {
    __builtin_amdgcn_global_load_lds(
        (const __attribute__((address_space(1))) void*)g,
        (__attribute__((address_space(3))) void*)l,
        16, 0, 0);
}

// anchor base sizes: ratios {0.5,1,2} x scales {8,16,32}
__constant__ float WBASE[9] = {184.f, 368.f, 736.f, 128.f, 256.f, 512.f,  88.f, 176.f, 352.f};
__constant__ float HBASE[9] = { 96.f, 192.f, 384.f, 128.f, 256.f, 512.f, 176.f, 352.f, 704.f};

// ---------------- fused prep: border + xpad-transpose + wt + wc ------------
// blocks [0,258): zero border; [258,4354): NCHW->NHWC bf16; [4354,4866): wt;
// [4866,4994): wc
__global__ __launch_bounds__(256) void prep_all(
    const float* __restrict__ x, const float* __restrict__ bw,
    const float* __restrict__ cls_w, const float* __restrict__ reg_w,
    u16* __restrict__ xpad, u16* __restrict__ wt, u16* __restrict__ wc) {
    __shared__ char ldsraw[18624];       // >= max(64*65*4, 9*1033*2) bytes
    const int b = blockIdx.x;
    const int tid = threadIdx.x;

    if (b < 258) {                       // ---- border zero (vectorized)
        int t = b * 256 + tid;           // 516*128 = 66048 chunks of 8 u16
        int cell = t >> 7, c8 = (t & 127) * 8;
        int h, w;
        if (cell < 130)      { h = 0;   w = cell; }
        else if (cell < 260) { h = 129; w = cell - 130; }
        else { int rm = cell - 260; h = 1 + (rm >> 1); w = (rm & 1) * 129; }
        s8v z = {};
        *(s8v*)&xpad[(h * XP + w) * CIN + c8] = z;
    } else if (b < 4354) {               // ---- x transpose+pad
        float (*lds)[65] = (float(*)[65])ldsraw;
        const int b2 = b - 258;
        const int h  = b2 >> 5;
        const int w0 = ((b2 >> 4) & 1) * 64;
        const int c0 = (b2 & 15) * 64;
        {
            const int wl = tid & 63, ci = tid >> 6;
            #pragma unroll
            for (int k = 0; k < 16; ++k) {
                int cl = ci * 16 + k;
                lds[cl][wl] = x[(c0 + cl) * (F * F) + h * F + (w0 + wl)];
            }
        }
        __syncthreads();
        {
            const int cs = (tid & 7) * 8;
            #pragma unroll
            for (int pass = 0; pass < 2; ++pass) {
                const int wl = (tid >> 3) + pass * 32;
                s8v v;
                #pragma unroll
                for (int j = 0; j < 8; ++j) v[j] = (short)f2bf(lds[cs + j][wl]);
                *(s8v*)&xpad[((h + 1) * XP + (w0 + wl + 1)) * CIN + c0 + cs] = v;
            }
        }
    } else if (b < 4866) {               // ---- base_w OIHW -> [oc][dydx][c]
        u16* lds = (u16*)ldsraw;         // stride 1033 to break bank conflicts
        const int oc = b - 4354;
        for (int k = 0; k < 36; ++k) {
            int idx = k * 256 + tid;     // (c,dydx) linear, c-major
            float v = bw[oc * K9 + idx];
            int c = idx / 9, q = idx - c * 9;
            lds[q * 1033 + c] = f2bf(v);
        }
        __syncthreads();
        for (int k = 0; k < 36; ++k) {
            int idx = k * 256 + tid;
            int q = idx >> 10, c = idx & 1023;
            wt[oc * K9 + idx] = lds[q * 1033 + c];
        }
    } else {                             // ---- combined 1x1 weights
        int t = (b - 4866) * 256 + tid;  // 64*512
        int oc = t >> 9, c = t & 511;
        float v = 0.f;
        if (oc < 18)      v = cls_w[oc * 512 + c];
        else if (oc < 54) v = reg_w[(oc - 18) * 512 + c];
        wc[t] = f2bf(v);
    }
}

// ---------------- stage 1: implicit-GEMM 3x3 conv + bias + ReLU ------------
// M=16384 (tile 128 = one image row), N=512 (tile 128), K=9216.
// Macro-step ms=(dy,cc): A[130][64] staged once, reused for dx=0,1,2 via row
// offset. B double-buffered per substep. XOR-swizzled LDS (source-side).
// XCD swizzle: blocks sharing oc0 pinned to a 2-XCD group.
__global__ __launch_bounds__(256, 2) void gemm_conv(
    const u16* __restrict__ xpad, const u16* __restrict__ wt,
    const float* __restrict__ bias, u16* __restrict__ rpn) {
    __shared__ u16 smem[2 * A_ELEMS + 2 * B_ELEMS];   // 67584 B
    const int tid = threadIdx.x;
    const int bid = blockIdx.x;
    const int oc0 = ((bid & 7) >> 1) * 128;
    const int gh  = (bid >> 3) * 2 + (bid & 1);

    const int lane = tid & 63;
    const int wv = tid >> 6;
    const int lm = lane & 15;
    const int lq = lane >> 4;
    const int wm = (wv >> 1) * 64;
    const int wn = (wv & 1) * 64;

    // source-side XOR swizzle: lane L stages data seg (L&7)^((L>>3)&7) of its row
    const int sw = (lane & 7) ^ ((lane >> 3) & 7);
    const u16* pA = xpad + (lane >> 3) * CIN + sw * 8;
    const u16* pB = wt + (size_t)(oc0 + wv * 32 + (lane >> 3)) * K9 + sw * 8;

    f4v acc[4][4] = {};

    // stage A tile for macro-step ms into Abuf[ms&1]: 136 rows (130 valid)
    auto issueA = [&](int ms) {
        const int dy = ms >> 4, cc = ms & 15;
        const u16* src = pA + ((gh + dy) * XP) * CIN + cc * 64;
        u16* dst = &smem[AOFF(ms & 1)];
        #pragma unroll
        for (int jj = 0; jj < 4; ++jj) {
            const int ci = wv * 4 + jj;
            gl16(src + ci * 8 * CIN, dst + ci * 512);
        }
        if (wv == 0) gl16(src + 16 * 8 * CIN, dst + 16 * 512);  // rows 128..135
    };
    // stage B tile for (ms,dx) into Bbuf[buf]
    auto issueB = [&](int ms, int dx, int buf) {
        const int dy = ms >> 4, cc = ms & 15;
        const int dydx = dy * 3 + dx;
        const u16* src = pB + dydx * CIN + cc * 64;
        u16* dst = &smem[BOFF(buf) + wv * 32 * 64];
        #pragma unroll
        for (int jj = 0; jj < 4; ++jj)
            gl16(src + jj * 8 * K9, dst + jj * 8 * 64);
    };

    issueA(0);
    issueB(0, 0, 0);
    __syncthreads();

    int t = 0;
    for (int ms = 0; ms < 48; ++ms) {
        const u16* Ab = &smem[AOFF(ms & 1)];
        #pragma unroll
        for (int dx = 0; dx < 3; ++dx, ++t) {
            if (t + 1 < 144) {
                const int msn = (dx == 2) ? ms + 1 : ms;
                const int dxn = (dx == 2) ? 0 : dx + 1;
                issueB(msn, dxn, (t + 1) & 1);
            }
            if (dx == 0 && ms + 1 < 48) issueA(ms + 1);
            const u16* Bb = &smem[BOFF(t & 1)];
            #pragma unroll
            for (int kk = 0; kk < 2; ++kk) {
                const int kseg = kk * 4 + lq;
                s8v af[4], bfr[4];
                #pragma unroll
                for (int i = 0; i < 4; ++i) {
                    const int ra = wm + i * 16 + lm + dx;
                    const int rb = wn + i * 16 + lm;
                    af[i]  = *(const s8v*)&Ab[ra * 64 + ((kseg ^ (ra & 7)) << 3)];
                    bfr[i] = *(const s8v*)&Bb[rb * 64 + ((kseg ^ (rb & 7)) << 3)];
                }
                #pragma unroll
                for (int mi = 0; mi < 4; ++mi)
                    #pragma unroll
                    for (int ni = 0; ni < 4; ++ni)
                        acc[mi][ni] = __builtin_amdgcn_mfma_f32_16x16x32_bf16(
                            af[mi], bfr[ni], acc[mi][ni], 0, 0, 0);
            }
            __syncthreads();
        }
    }

    // epilogue: D[m][n]: m = lq*4+rr (+16mi+wm), n = lm (+16ni+wn)
    #pragma unroll
    for (int ni = 0; ni < 4; ++ni) {
        const int oc = oc0 + wn + ni * 16 + lm;
        const float bv = bias[oc];
        #pragma unroll
        for (int mi = 0; mi < 4; ++mi) {
            #pragma unroll
            for (int rr = 0; rr < 4; ++rr) {
                const int m = wm + mi * 16 + lq * 4 + rr;   // w index
                float v = acc[mi][ni][rr] + bv;
                v = v > 0.f ? v : 0.f;
                rpn[(gh * 128 + m) * CMID + oc] = f2bf(v);
            }
        }
    }
}

// ---------------- stage 2+3: 1x1 convs (MFMA) + softmax + proposals --------
// M=16384 (64/block, 16/wave), N=64 (18 cls + 36 reg + 10 pad), K=512.
__global__ __launch_bounds__(256) void stage23(
    const u16* __restrict__ rpn, const u16* __restrict__ wc,
    const float* __restrict__ cls_b, const float* __restrict__ reg_b,
    float* __restrict__ out) {
    __shared__ float vals[64][65];
    const int tid = threadIdx.x, lane = tid & 63, wv = tid >> 6;
    const int lm = lane & 15, lq = lane >> 4;
    const int m0 = blockIdx.x * 64 + wv * 16;
    f4v acc[4] = {};
    const u16* arow = rpn + (m0 + lm) * CMID + lq * 8;
    const u16* brow = wc + lm * CMID + lq * 8;
    #pragma unroll
    for (int k = 0; k < 16; ++k) {
        s8v af = *(const s8v*)(arow + k * 32);
        #pragma unroll
        for (int ni = 0; ni < 4; ++ni) {
            s8v bf = *(const s8v*)(brow + ni * 16 * CMID + k * 32);
            acc[ni] = __builtin_amdgcn_mfma_f32_16x16x32_bf16(af, bf, acc[ni], 0, 0, 0);
        }
    }
    #pragma unroll
    for (int ni = 0; ni < 4; ++ni) {
        const int ch = ni * 16 + lm;
        const float bv = ch < 18 ? cls_b[ch] : (ch < 54 ? reg_b[ch - 18] : 0.f);
        #pragma unroll
        for (int rr = 0; rr < 4; ++rr)
            vals[wv * 16 + lq * 4 + rr][ch] = acc[ni][rr] + bv;
    }
    __syncthreads();
    const int pbase = blockIdx.x * 64;
    for (int q = tid; q < 576; q += 256) {
        const int pl = q / 9, a = q - pl * 9;
        const float* v = vals[pl];
        const int ch = 2 * a + 1;
        const int pair = (ch < 9) ? ch + 9 : ch - 9;
        const float score = 1.f / (1.f + expf(v[pair] - v[ch]));
        const float r0 = v[18 + 4 * a], r1 = v[19 + 4 * a];
        const float r2 = v[20 + 4 * a], r3 = v[21 + 4 * a];
        const float wb = WBASE[a], hb = HBASE[a];
        const int p = pbase + pl;
        const int h = p >> 7, w = p & 127;
        float* o = out + (p * 9 + a) * 5;
        o[0] = h * 16.f + wb * r0;
        o[1] = w * 16.f + hb * r1;
        o[2] = wb + expf(r2);
        o[3] = hb + expf(r3);
        o[4] = score;
    }
}

extern "C" void kernel_launch(void* const* d_in, const int* in_sizes, int n_in,
                              void* d_out, int out_size, void* d_ws, size_t ws_size,
                              hipStream_t stream) {
    const float* x      = (const float*)d_in[0];
    const float* base_w = (const float*)d_in[1];
    const float* base_b = (const float*)d_in[2];
    const float* cls_w  = (const float*)d_in[3];
    const float* cls_b  = (const float*)d_in[4];
    const float* reg_w  = (const float*)d_in[5];
    const float* reg_b  = (const float*)d_in[6];
    float* out = (float*)d_out;

    char* ws = (char*)d_ws;
    u16* xpad = (u16*)ws;                                   // 130*130*1024*2 = 34,611,200 B
    u16* wt   = (u16*)(ws + 34611200);                      // 512*9216*2     =  9,437,184 B
    u16* wc   = (u16*)(ws + 34611200 + 9437184);            // 64*512*2       =     65,536 B
    u16* rpn  = (u16*)(ws + 34611200 + 9437184 + 65536);    // 16384*512*2    = 16,777,216 B

    prep_all<<<4994, 256, 0, stream>>>(x, base_w, cls_w, reg_w, xpad, wt, wc);
    gemm_conv<<<512, 256, 0, stream>>>(xpad, wt, base_b, rpn);
    stage23<<<256, 256, 0, stream>>>(rpn, wc, cls_b, reg_b, out);
}